// Round 4
// baseline (368.066 us; speedup 1.0000x reference)
//
#include <hip/hip_runtime.h>

// CavityModel forward (all f32): gaussian blur -> 3x(conv3d+maxpool+BN(batch
// stats)+leaky) -> dense 64->128 (+BN+leaky) -> 128->100 (+leaky) -> 100->20.
// R4: split splat/conv1 (occupancy), X-tiled conv1 (2 blocks/CU), oc-split conv2.

#define G2 324
#define G3 5832
#define NT 6
#define BATCH 256
#define APE 100
#define EPS 1e-5f

typedef unsigned short u16;
typedef unsigned int u32;

__device__ __forceinline__ float leaky(float x) { return x >= 0.0f ? x : 0.01f * x; }
__device__ __forceinline__ u16 f2b(float f) {
    union { float f; u32 u; } v; v.f = f;
    return (u16)((v.u + 0x7FFFu + ((v.u >> 16) & 1u)) >> 16);
}
__device__ __forceinline__ float b2f(u16 u) {
    union { u32 u; float f; } v; v.u = ((u32)u) << 16; return v.f;
}

// ---------- K1a: gaussian splat (separable, 9^3 window) -> fields (global)
// one block per env; field [6][18^3] in LDS; flattened atom*window item loop.
template <int BF16F>
__global__ __launch_bounds__(512) void k_splat(const float* __restrict__ pos,
        const int* __restrict__ types, void* __restrict__ fieldsv) {
    __shared__ float fld[NT * G3];   // 139968 B
    __shared__ float ew[APE * 27];   // [atom][axis][9], normalizer folded per-axis
    __shared__ short i0a[APE * 3];
    __shared__ int   tt[APE];
    const int b = blockIdx.x, tid = threadIdx.x;

    for (int i = tid; i < NT * G3; i += 512) fld[i] = 0.0f;
    if (tid < 300) {
        const int la = tid / 3, ax = tid % 3;
        const float p = pos[(b * APE + la) * 3 + ax];
        int i0 = (int)ceilf(p + 4.0f);
        i0 = max(0, min(9, i0));
        i0a[tid] = (short)i0;
        float e[18], s = 0.0f;
        #pragma unroll
        for (int g = 0; g < 18; ++g) {
            float d = (float)g - 8.5f - p;
            e[g] = __expf(d * d * (-1.0f / 0.72f));
            s += e[g];
        }
        const float inv = 1.0f / s;
        #pragma unroll
        for (int q = 0; q < 9; ++q) ew[la * 27 + ax * 9 + q] = e[i0 + q] * inv;
    }
    if (tid < APE) tt[tid] = types[b * APE + tid];
    __syncthreads();

    for (int idx = tid; idx < APE * 729; idx += 512) {
        const int la = idx / 729, r = idx % 729;
        const int di = r / 81, r2 = r % 81, dj = r2 / 9, dk = r2 % 9;
        const int i = i0a[la * 3] + di, j = i0a[la * 3 + 1] + dj, k = i0a[la * 3 + 2] + dk;
        atomicAdd(&fld[tt[la] * G3 + i * G2 + j * 18 + k],
                  ew[la * 27 + di] * ew[la * 27 + 9 + dj] * ew[la * 27 + 18 + dk]);
    }
    __syncthreads();

    if (BF16F) {
        u32* dst = (u32*)fieldsv + (size_t)b * (NT * G3 / 2);
        for (int i = tid; i < NT * G3 / 2; i += 512)
            dst[i] = (u32)f2b(fld[2 * i]) | ((u32)f2b(fld[2 * i + 1]) << 16);
    } else {
        float4* dst = (float4*)((float*)fieldsv + (size_t)b * NT * G3);
        const float4* s4 = (const float4*)fld;
        for (int i = tid; i < NT * G3 / 4; i += 512) dst[i] = s4[i];
    }
}

// ---------- K1b: conv1 (6->16, pad1) + maxpool2 + bias + bn1 stats, X-tiled
// grid = 3 * BATCH; b = bx & 255, g = bx >> 8 (same-XCD field sharing).
// LDS: 8 x-planes (halo zero-padded) * 6 ch * 324 = 62 KB -> 2 blocks/CU.
template <int BF16F>
__global__ __launch_bounds__(448) void k_conv1(const void* __restrict__ fieldsv,
        const float* __restrict__ w, const float* __restrict__ bias,
        float* __restrict__ a1, float* __restrict__ stO) {
    __shared__ float fldT[6 * 8 * 324];  // 62208 B, [ic][ixl][324]
    __shared__ float ws1[2592];          // 16*6*27
    __shared__ float bs[16], s_sum[16], s_ssq[16];
    const int bx = blockIdx.x, b = bx & 255, g = bx >> 8, tid = threadIdx.x;

    if (BF16F) {
        const u32* src = (const u32*)fieldsv;
        for (int i = tid; i < 6 * 8 * 162; i += 448) {   // pair index
            const int p = i / 162, offp = i % 162;
            const int ic = p >> 3, ixl = p & 7, ix = 6 * g - 1 + ixl;
            float lo = 0.0f, hi = 0.0f;
            if (ix >= 0 && ix <= 17) {
                const u32 v = src[((size_t)(b * 6 + ic) * 18 + ix) * 162 + offp];
                lo = b2f((u16)v); hi = b2f((u16)(v >> 16));
            }
            fldT[2 * i] = lo; fldT[2 * i + 1] = hi;
        }
    } else {
        const float* src = (const float*)fieldsv;
        for (int i = tid; i < 6 * 8 * 324; i += 448) {
            const int p = i / 324, off = i % 324;
            const int ic = p >> 3, ixl = p & 7, ix = 6 * g - 1 + ixl;
            fldT[i] = (ix >= 0 && ix <= 17)
                    ? src[((size_t)(b * 6 + ic) * 18 + ix) * 324 + off] : 0.0f;
        }
    }
    for (int i = tid; i < 2592; i += 448) ws1[i] = w[i];
    if (tid < 16) { bs[tid] = bias[tid]; s_sum[tid] = 0.0f; s_ssq[tid] = 0.0f; }
    __syncthreads();

    // item: oyi=bit0, oxi=bit1, Y(9), Xl(3), c4(4) -> 432 items, one pass
    if (tid < 432) {
        const int idx = tid;
        const int oyi = idx & 1, oxi = (idx >> 1) & 1, rest = idx >> 2;
        const int Y = rest % 9, Xl = (rest / 9) % 3, c4 = rest / 27;
        const int oy = 2 * Y + oyi;
        float acc[4][18];
        #pragma unroll
        for (int cc = 0; cc < 4; ++cc)
            #pragma unroll
            for (int z = 0; z < 18; ++z) acc[cc][z] = 0.0f;
        for (int ic = 0; ic < 6; ++ic) {
            #pragma unroll
            for (int dx = 0; dx < 3; ++dx) {
                const int ixl = 2 * Xl + oxi + dx;       // 0..7, pad pre-zeroed
                #pragma unroll
                for (int dy = 0; dy < 3; ++dy) {
                    const int iy = oy + dy - 1;
                    if (iy < 0 || iy > 17) continue;
                    const float2* rp2 =
                        (const float2*)&fldT[((ic << 3) + ixl) * 324 + iy * 18];
                    float row[18];
                    #pragma unroll
                    for (int j = 0; j < 9; ++j) {
                        const float2 t2 = rp2[j];
                        row[2 * j] = t2.x; row[2 * j + 1] = t2.y;
                    }
                    float wv[4][3];
                    #pragma unroll
                    for (int cc = 0; cc < 4; ++cc)
                        #pragma unroll
                        for (int dz = 0; dz < 3; ++dz)
                            wv[cc][dz] = ws1[((c4 * 4 + cc) * 6 + ic) * 27
                                             + dx * 9 + dy * 3 + dz];
                    #pragma unroll
                    for (int dz = 0; dz < 3; ++dz) {
                        #pragma unroll
                        for (int z = 0; z < 18; ++z) {
                            const int iz = z + dz - 1;
                            if (iz >= 0 && iz < 18) {
                                #pragma unroll
                                for (int cc = 0; cc < 4; ++cc)
                                    acc[cc][z] += wv[cc][dz] * row[iz];
                            }
                        }
                    }
                }
            }
        }
        float pl[4][9];
        #pragma unroll
        for (int cc = 0; cc < 4; ++cc)
            #pragma unroll
            for (int Z = 0; Z < 9; ++Z) {
                float v = fmaxf(acc[cc][2 * Z], acc[cc][2 * Z + 1]);
                v = fmaxf(v, __shfl_xor(v, 1));
                v = fmaxf(v, __shfl_xor(v, 2));
                pl[cc][Z] = v;
            }
        if ((idx & 3) == 0) {
            const int Xg = 3 * g + Xl;
            #pragma unroll
            for (int cc = 0; cc < 4; ++cc) {
                const int c = c4 * 4 + cc;
                const float bb = bs[c];
                float s0 = 0.0f, q0 = 0.0f;
                float* o = &a1[((size_t)b * 16 + c) * 729 + Xg * 81 + Y * 9];
                #pragma unroll
                for (int Z = 0; Z < 9; ++Z) {
                    const float v = pl[cc][Z] + bb;
                    o[Z] = v;
                    s0 += v; q0 += v * v;
                }
                atomicAdd(&s_sum[c], s0); atomicAdd(&s_ssq[c], q0);
            }
        }
    }
    __syncthreads();
    if (tid < 16) { atomicAdd(&stO[tid], s_sum[tid]); atomicAdd(&stO[16 + tid], s_ssq[tid]); }
}

// ---------- K2: bn1+leaky -> conv2 (16->32, pad0) + pool -> [32,3^3] + bn2 stats
// grid = 2 * BATCH over oc-halves; LDS 74 KB -> 2 blocks/CU; quad-shfl pooling.
__global__ __launch_bounds__(320) void k_conv2(const float* __restrict__ a1,
        const float* __restrict__ w, const float* __restrict__ bias,
        const float* __restrict__ bng, const float* __restrict__ bnb,
        const float* __restrict__ stI, float* __restrict__ a2,
        float* __restrict__ stO) {
    __shared__ float xin[16 * 729];   // 46656 B
    __shared__ float ws2[16 * 16 * 27]; // half of weights: 27648 B
    __shared__ float sc[16], sh[16];
    __shared__ float s_sum[16], s_ssq[16];
    const int bx = blockIdx.x, b = bx & 255, half = bx >> 8, tid = threadIdx.x;
    if (tid < 16) {
        const float cnt = 256.0f * 729.0f;
        float m = stI[tid] / cnt;
        float v = stI[16 + tid] / cnt - m * m;
        float s = bng[tid] * rsqrtf(fmaxf(v, 0.0f) + EPS);
        sc[tid] = s; sh[tid] = bnb[tid] - m * s;
        s_sum[tid] = 0.0f; s_ssq[tid] = 0.0f;
    }
    __syncthreads();
    const float* src = a1 + (size_t)b * 16 * 729;
    for (int i = tid; i < 16 * 729; i += 320) {
        int c = i / 729;
        xin[i] = leaky(src[i] * sc[c] + sh[c]);
    }
    for (int i = tid; i < 6912; i += 320) ws2[i] = w[half * 6912 + i];
    __syncthreads();
    // item: oyi=bit0, oxi=bit1, Y(3), X(3), c2l(8) = 288 items, one pass
    if (tid < 288) {
        const int idx = tid;
        const int oyi = idx & 1, oxi = (idx >> 1) & 1, rest = idx >> 2;
        const int Y = rest % 3, X = (rest / 3) % 3, c2l = rest / 9;
        const int ox = 2 * X + oxi, oy = 2 * Y + oyi;   // 0..5
        const int cl0 = 2 * c2l, cl1 = cl0 + 1;
        float acc0[6], acc1[6];
        #pragma unroll
        for (int z = 0; z < 6; ++z) { acc0[z] = 0.0f; acc1[z] = 0.0f; }
        for (int ic = 0; ic < 16; ++ic) {
            #pragma unroll
            for (int dx = 0; dx < 3; ++dx) {
                const int ix = ox + dx;
                #pragma unroll
                for (int dy = 0; dy < 3; ++dy) {
                    const int iy = oy + dy;
                    const float* rp = &xin[ic * 729 + ix * 81 + iy * 9];
                    float row[9];
                    #pragma unroll
                    for (int z = 0; z < 9; ++z) row[z] = rp[z];
                    const int wb0 = (cl0 * 16 + ic) * 27 + dx * 9 + dy * 3;
                    const int wb1 = (cl1 * 16 + ic) * 27 + dx * 9 + dy * 3;
                    #pragma unroll
                    for (int dz = 0; dz < 3; ++dz) {
                        const float w0 = ws2[wb0 + dz];
                        const float w1v = ws2[wb1 + dz];
                        #pragma unroll
                        for (int z = 0; z < 6; ++z) {
                            acc0[z] += w0 * row[z + dz];
                            acc1[z] += w1v * row[z + dz];
                        }
                    }
                }
            }
        }
        float pl[2][3];
        #pragma unroll
        for (int Z = 0; Z < 3; ++Z) {
            float v0 = fmaxf(acc0[2 * Z], acc0[2 * Z + 1]);
            float v1 = fmaxf(acc1[2 * Z], acc1[2 * Z + 1]);
            v0 = fmaxf(v0, __shfl_xor(v0, 1)); v0 = fmaxf(v0, __shfl_xor(v0, 2));
            v1 = fmaxf(v1, __shfl_xor(v1, 1)); v1 = fmaxf(v1, __shfl_xor(v1, 2));
            pl[0][Z] = v0; pl[1][Z] = v1;
        }
        if ((idx & 3) == 0) {
            #pragma unroll
            for (int h = 0; h < 2; ++h) {
                const int cl = cl0 + h, c = half * 16 + cl;
                const float bb = bias[c];
                #pragma unroll
                for (int Z = 0; Z < 3; ++Z) {
                    const float v = pl[h][Z] + bb;
                    a2[((size_t)b * 32 + c) * 27 + X * 9 + Y * 3 + Z] = v;
                    atomicAdd(&s_sum[cl], v); atomicAdd(&s_ssq[cl], v * v);
                }
            }
        }
    }
    __syncthreads();
    if (tid < 16) {
        const int c = half * 16 + tid;
        atomicAdd(&stO[c], s_sum[tid]); atomicAdd(&stO[32 + c], s_ssq[tid]);
    }
}

// ---------- K3: bn2+leaky -> conv3 (32->64, pad1, 3^3) + pool -> [64] + bn3 stats
__global__ __launch_bounds__(256) void k_conv3(const float* __restrict__ a2,
        const float* __restrict__ w, const float* __restrict__ bias,
        const float* __restrict__ bng, const float* __restrict__ bnb,
        const float* __restrict__ stI, float* __restrict__ a3,
        float* __restrict__ stO) {
    __shared__ float x[864];
    __shared__ float pacc[256 * 8];
    __shared__ float sc[32], sh[32];
    const int b = blockIdx.x, tid = threadIdx.x;
    if (tid < 32) {
        const float cnt = 256.0f * 27.0f;
        float m = stI[tid] / cnt;
        float v = stI[32 + tid] / cnt - m * m;
        float s = bng[tid] * rsqrtf(fmaxf(v, 0.0f) + EPS);
        sc[tid] = s; sh[tid] = bnb[tid] - m * s;
    }
    __syncthreads();
    for (int i = tid; i < 864; i += 256) {
        int c = i / 27;
        x[i] = leaky(a2[(size_t)b * 864 + i] * sc[c] + sh[c]);
    }
    __syncthreads();
    const int c = tid & 63, q = tid >> 6;
    float acc[8];
    #pragma unroll
    for (int p = 0; p < 8; ++p) acc[p] = 0.0f;
    for (int ic = q * 8; ic < q * 8 + 8; ++ic) {
        const float* wr = w + ((size_t)c * 32 + ic) * 27;
        #pragma unroll
        for (int d = 0; d < 27; ++d) {
            const int dx = d / 9, dy = (d / 3) % 3, dz = d % 3;
            const float wv = wr[d];
            #pragma unroll
            for (int p = 0; p < 8; ++p) {
                const int px = p >> 2, py = (p >> 1) & 1, pz = p & 1;
                const int ix = px + dx - 1, iy = py + dy - 1, iz = pz + dz - 1;
                if (ix >= 0 && iy >= 0 && iz >= 0)
                    acc[p] += wv * x[ic * 27 + ix * 9 + iy * 3 + iz];
            }
        }
    }
    #pragma unroll
    for (int p = 0; p < 8; ++p) pacc[tid * 8 + p] = acc[p];
    __syncthreads();
    if (q == 0) {
        float m = -1e30f;
        #pragma unroll
        for (int p = 0; p < 8; ++p) {
            float v = pacc[c * 8 + p] + pacc[(64 + c) * 8 + p]
                    + pacc[(128 + c) * 8 + p] + pacc[(192 + c) * 8 + p];
            m = fmaxf(m, v);
        }
        float v = m + bias[c];
        a3[(size_t)b * 64 + c] = v;
        atomicAdd(&stO[c], v); atomicAdd(&stO[64 + c], v * v);
    }
}

// ---------- K4: bn3+leaky -> dense 64->128 (pre-bn4) + bn4 stats
__global__ __launch_bounds__(128) void k_dense1(const float* __restrict__ a3,
        const float* __restrict__ bng, const float* __restrict__ bnb,
        const float* __restrict__ stI,
        const float* __restrict__ w1, const float* __restrict__ b1,
        float* __restrict__ h1, float* __restrict__ stO) {
    __shared__ float x[64];
    const int b = blockIdx.x, tid = threadIdx.x;
    if (tid < 64) {
        float m = stI[tid] / 256.0f;
        float v = stI[64 + tid] / 256.0f - m * m;
        float s = bng[tid] * rsqrtf(fmaxf(v, 0.0f) + EPS);
        x[tid] = leaky(a3[(size_t)b * 64 + tid] * s + (bnb[tid] - m * s));
    }
    __syncthreads();
    const float* wr = w1 + tid * 64;
    float acc = b1[tid];
    #pragma unroll
    for (int i = 0; i < 64; ++i) acc += x[i] * wr[i];
    h1[(size_t)b * 128 + tid] = acc;
    atomicAdd(&stO[tid], acc); atomicAdd(&stO[128 + tid], acc * acc);
}

// ---------- K5: bn4+leaky -> 128->100 (+leaky) -> 100->20 -> out (f32)
__global__ __launch_bounds__(128) void k_dense2(const float* __restrict__ h1,
        const float* __restrict__ bng, const float* __restrict__ bnb,
        const float* __restrict__ stI,
        const float* __restrict__ w2, const float* __restrict__ bias2,
        const float* __restrict__ w3, const float* __restrict__ bias3,
        float* __restrict__ out) {
    __shared__ float x[128];
    __shared__ float y[100];
    const int b = blockIdx.x, tid = threadIdx.x;
    {
        float m = stI[tid] / 256.0f;
        float v = stI[128 + tid] / 256.0f - m * m;
        float s = bng[tid] * rsqrtf(fmaxf(v, 0.0f) + EPS);
        x[tid] = leaky(h1[(size_t)b * 128 + tid] * s + (bnb[tid] - m * s));
    }
    __syncthreads();
    if (tid < 100) {
        const float* wr = w2 + tid * 128;
        float acc = bias2[tid];
        #pragma unroll
        for (int i = 0; i < 128; ++i) acc += x[i] * wr[i];
        y[tid] = leaky(acc);
    }
    __syncthreads();
    if (tid < 20) {
        const float* wr = w3 + tid * 100;
        float acc = bias3[tid];
        #pragma unroll
        for (int i = 0; i < 100; ++i) acc += y[i] * wr[i];
        out[(size_t)b * 20 + tid] = acc;
    }
}

extern "C" void kernel_launch(void* const* d_in, const int* in_sizes, int n_in,
                              void* d_out, int out_size, void* d_ws, size_t ws_size,
                              hipStream_t stream) {
    (void)in_sizes; (void)n_in; (void)out_size;
    const float* pos  = (const float*)d_in[0];
    const float* c1w  = (const float*)d_in[1];
    const float* c1b  = (const float*)d_in[2];
    const float* bn1g = (const float*)d_in[3];
    const float* bn1b = (const float*)d_in[4];
    const float* c2w  = (const float*)d_in[5];
    const float* c2b  = (const float*)d_in[6];
    const float* bn2g = (const float*)d_in[7];
    const float* bn2b = (const float*)d_in[8];
    const float* c3w  = (const float*)d_in[9];
    const float* c3b  = (const float*)d_in[10];
    const float* bn3g = (const float*)d_in[11];
    const float* bn3b = (const float*)d_in[12];
    const float* d1w  = (const float*)d_in[13];
    const float* d1b  = (const float*)d_in[14];
    const float* bn4g = (const float*)d_in[15];
    const float* bn4b = (const float*)d_in[16];
    const float* d2w  = (const float*)d_in[17];
    const float* d2b  = (const float*)d_in[18];
    const float* d3w  = (const float*)d_in[19];
    const float* d3b  = (const float*)d_in[20];
    const int* types  = (const int*)d_in[22];   // d_in[21]=batch_ids implied by layout

    float* ws = (float*)d_ws;
    float* st = ws;                         // 480 f (bn stats)
    float* a3 = ws + 512;                   // 16,384 f
    float* h1 = a3 + 16384;                 // 32,768 f
    float* a2 = h1 + 32768;                 // 221,184 f
    float* a1 = a2 + 221184;                // 2,985,984 f
    void*  fields = (void*)(a1 + 2985984);  // f32: 8,957,952 f  (total ~49 MB)

    const size_t need_f32 = (512 + 16384 + 32768 + 221184 + 2985984
                             + (size_t)BATCH * NT * G3) * 4;
    const int bf16f = (ws_size < need_f32) ? 1 : 0;

    hipMemsetAsync(st, 0, 480 * sizeof(float), stream);
    if (bf16f) {
        k_splat<1><<<BATCH, 512, 0, stream>>>(pos, types, fields);
        k_conv1<1><<<3 * BATCH, 448, 0, stream>>>(fields, c1w, c1b, a1, st);
    } else {
        k_splat<0><<<BATCH, 512, 0, stream>>>(pos, types, fields);
        k_conv1<0><<<3 * BATCH, 448, 0, stream>>>(fields, c1w, c1b, a1, st);
    }
    k_conv2 <<<2 * BATCH, 320, 0, stream>>>(a1, c2w, c2b, bn1g, bn1b, st, a2, st + 32);
    k_conv3 <<<BATCH, 256, 0, stream>>>(a2, c3w, c3b, bn2g, bn2b, st + 32, a3, st + 96);
    k_dense1<<<BATCH, 128, 0, stream>>>(a3, bn3g, bn3b, st + 96, d1w, d1b, h1, st + 224);
    k_dense2<<<BATCH, 128, 0, stream>>>(h1, bn4g, bn4b, st + 224, d2w, d2b, d3w, d3b,
                                        (float*)d_out);
}